// Round 8
// baseline (556.412 us; speedup 1.0000x reference)
//
#include <hip/hip_runtime.h>
#include <hip/hip_bf16.h>

// LinearPreMix: qkv = x @ W_qkv^T, split to q,k,v, reshape [B,S,E]->[B,H,S,DK]
// Pass 1: cast x,W fp32->bf16 into d_ws.
// Pass 2: r8 TLP GEMM — 128x128 tile, 256 threads, single-buffered 32 KB LDS,
//         4 independent blocks/CU (4 waves/SIMD from different blocks).
//         Rationale: r4-r7 all pinned at MfmaUtil 44-48% with 1 block/CU and
//         block-lockstep barriers; TLP lets sibling blocks fill the per-tile
//         stage/wait bubble (m114 MFMA/VALU co-schedule mechanism).

constexpr int Bb = 4, Ss = 4096, Ee = 2048, Hh = 16, Dk = 128;
constexpr int Mm = Bb * Ss;   // 16384
constexpr int Nn = 3 * Ee;    // 6144
constexpr int Kk = Ee;        // 2048

typedef __bf16 bf16_t;
typedef __bf16 bf16x8 __attribute__((ext_vector_type(8)));
typedef float  f32x4  __attribute__((ext_vector_type(4)));

// ---------------------------------------------------------------- cast pass
__global__ __launch_bounds__(256)
void cast_f32_to_bf16(const float* __restrict__ x, const float* __restrict__ w,
                      bf16_t* __restrict__ xb, bf16_t* __restrict__ wb)
{
    const long XG = (long)Mm * Kk / 8;
    const long TG = XG + (long)Nn * Kk / 8;
    const long stride = (long)gridDim.x * blockDim.x;
    for (long g = (long)blockIdx.x * blockDim.x + threadIdx.x; g < TG; g += stride) {
        const float* s; bf16_t* d;
        if (g < XG) { s = x + g * 8;        d = xb + g * 8; }
        else        { s = w + (g - XG) * 8; d = wb + (g - XG) * 8; }
        f32x4 lo = *(const f32x4*)s;
        f32x4 hi = *(const f32x4*)(s + 4);
        bf16x8 o;
#pragma unroll
        for (int j = 0; j < 4; ++j) { o[j] = (bf16_t)lo[j]; o[j + 4] = (bf16_t)hi[j]; }
        *(bf16x8*)d = o;
    }
}

// --------------------------------------------------- TLP 128² single-buffer
constexpr int TBM = 128, TBN = 128, TBK = 64;
constexpr int TNBM = Mm / TBM;        // 128
constexpr int TNBN = Nn / TBN;        // 48
constexpr int TNWG = TNBM * TNBN;     // 6144
constexpr int TNKT = Kk / TBK;        // 32

#define GLL16(GSRC, LDST) \
  __builtin_amdgcn_global_load_lds((const __attribute__((address_space(1))) void*)(GSRC), \
                                   (__attribute__((address_space(3))) void*)(LDST), 16, 0, 0)

__global__ __launch_bounds__(256, 4)
void qkv_tlp(const bf16_t* __restrict__ xb, const bf16_t* __restrict__ wb,
             float* __restrict__ out)
{
    // single-buffered tiles: 2 kh slices x (128 rows x 32 k) each, 16 KB/operand
    __shared__ __attribute__((aligned(16))) bf16_t sA[8192];
    __shared__ __attribute__((aligned(16))) bf16_t sB[8192];

    const int tid  = threadIdx.x;
    const int lane = tid & 63;
    const int wid  = tid >> 6;     // 0..3 (one wave per SIMD)
    const int wm2  = wid >> 1;     // 0..1 (64-row half)
    const int wn2  = wid & 1;      // 0..1 (64-col half)
    const int kc   = lane >> 4;    // frag k-chunk 0..3

    // XCD-striped mapping: A panels L2-local per XCD, B panels chip-shared.
    const int xcd = blockIdx.x & 7;
    const int i   = blockIdx.x >> 3;     // 0..767
    const int bn  = i % TNBN;            // 0..47
    const int bm  = xcd * 16 + i / TNBN; // 0..127
    const int m0 = bm * TBM, n0 = bn * TBN;

    // pre-swizzled staging sources (linear LDS dest + swizzled global source).
    // chunk c (0..511 per slice): row r=c>>2, stored pos p=c&3,
    // logical col cl = p ^ ((r>>1)&3).  thread t covers c=t and c=t+256
    // (r and r+64 share the same ((r>>1)&3) since 32 ≡ 0 mod 4).
    const int r0  = tid >> 2;                       // 0..63
    const int cl0 = (tid & 3) ^ ((r0 >> 1) & 3);
    const bf16_t* srcA0 = xb + (size_t)(m0 + r0) * Kk + cl0 * 8;
    const bf16_t* srcA1 = srcA0 + (size_t)64 * Kk;
    const bf16_t* srcB0 = wb + (size_t)(n0 + r0) * Kk + cl0 * 8;
    const bf16_t* srcB1 = srcB0 + (size_t)64 * Kk;

    f32x4 acc[4][4] = {};

#pragma unroll 1
    for (int kt = 0; kt < TNKT; ++kt) {
        const int ko = kt * TBK;

        // all waves done reading previous tile (own reads drained by MFMA
        // waitcnts; lgkm(0) is free if already drained)
        asm volatile("s_waitcnt lgkmcnt(0)" ::: "memory");
        __builtin_amdgcn_sched_barrier(0);
        __builtin_amdgcn_s_barrier();

        // stage this K-tile: 8 x GLL16 per thread (A,B x 2 kh-slices x 2 rows)
        {
            bf16_t* dA = sA + wid * 512;
            bf16_t* dB = sB + wid * 512;
            GLL16(srcA0 + ko,      dA);
            GLL16(srcA1 + ko,      dA + 2048);
            GLL16(srcA0 + ko + 32, dA + 4096);
            GLL16(srcA1 + ko + 32, dA + 6144);
            GLL16(srcB0 + ko,      dB);
            GLL16(srcB1 + ko,      dB + 2048);
            GLL16(srcB0 + ko + 32, dB + 4096);
            GLL16(srcB1 + ko + 32, dB + 6144);
        }
        asm volatile("s_waitcnt vmcnt(0)" ::: "memory");
        __builtin_amdgcn_sched_barrier(0);
        __builtin_amdgcn_s_barrier();

        // compute: 2 K32 slices x 16 MFMA
#pragma unroll
        for (int ks = 0; ks < 2; ++ks) {
            bf16x8 a[4], b[4];
#pragma unroll
            for (int mf = 0; mf < 4; ++mf) {
                int r = wm2 * 64 + mf * 16 + (lane & 15);
                int q = r * 4 + (kc ^ ((r >> 1) & 3));
                a[mf] = *(const bf16x8*)(sA + ks * 4096 + q * 8);
            }
#pragma unroll
            for (int nf = 0; nf < 4; ++nf) {
                int cr = wn2 * 64 + nf * 16 + (lane & 15);
                int q = cr * 4 + (kc ^ ((cr >> 1) & 3));
                b[nf] = *(const bf16x8*)(sB + ks * 4096 + q * 8);
            }
            __builtin_amdgcn_s_setprio(1);
#pragma unroll
            for (int mf = 0; mf < 4; ++mf)
#pragma unroll
                for (int nf = 0; nf < 4; ++nf)
                    acc[mf][nf] = __builtin_amdgcn_mfma_f32_16x16x32_bf16(
                        a[mf], b[nf], acc[mf][nf], 0, 0, 0);
            __builtin_amdgcn_s_setprio(0);
        }
    }

    // epilogue: tile cols live in exactly one (which,b,h) panel (DK=128).
    // nt stores, line-contiguous (mf,r,nf) order.
    const int which = n0 >> 11;
    const int hh    = (n0 & (Ee - 1)) >> 7;
    const int bbx   = m0 >> 12;
    const int srow  = (m0 & (Ss - 1)) + wm2 * 64;
    float* obase = out + (((size_t)(which * Bb + bbx) * Hh + hh) * Ss + srow) * Dk
                 + wn2 * 64;

#pragma unroll
    for (int mf = 0; mf < 4; ++mf)
#pragma unroll
        for (int r = 0; r < 4; ++r)
#pragma unroll
            for (int nf = 0; nf < 4; ++nf) {
                const int row = mf * 16 + (lane >> 4) * 4 + r;
                const int col = nf * 16 + (lane & 15);
                __builtin_nontemporal_store(acc[mf][nf][r],
                                            &obase[(size_t)row * Dk + col]);
            }
}

// ------------------------------------------- fallback (fp32 reg staging)
constexpr int FTM = 128, FTN = 128, FTK = 64;
constexpr int FNKT = Kk / FTK;

__global__ __launch_bounds__(256, 2)
void qkv_gemm_fb(const float* __restrict__ x, const float* __restrict__ w,
                 float* __restrict__ out)
{
    __shared__ __attribute__((aligned(16))) bf16_t lA[2][FTM * FTK];
    __shared__ __attribute__((aligned(16))) bf16_t lB[2][FTN * FTK];

    const int tid = threadIdx.x, lane = tid & 63, wid = tid >> 6;
    const int wm = wid >> 1, wn = wid & 1;
    const int n0 = blockIdx.x * FTN, m0 = blockIdx.y * FTM;
    f32x4 ra[8], rb[8];

    auto load_regs = [&](int kt) {
        const int k0 = kt * FTK;
#pragma unroll
        for (int i = 0; i < 4; ++i) {
            const int c = tid + i * 256, row = c >> 3, cir = c & 7;
            const float* pa = x + (size_t)(m0 + row) * Kk + k0 + cir * 8;
            const float* pb = w + (size_t)(n0 + row) * Kk + k0 + cir * 8;
            ra[i*2+0] = *(const f32x4*)(pa); ra[i*2+1] = *(const f32x4*)(pa+4);
            rb[i*2+0] = *(const f32x4*)(pb); rb[i*2+1] = *(const f32x4*)(pb+4);
        }
    };
    auto store_lds = [&](int buf) {
#pragma unroll
        for (int i = 0; i < 4; ++i) {
            const int c = tid + i * 256, row = c >> 3, cir = c & 7;
            const int chunk = row * 8 + (cir ^ (row & 7));
            bf16x8 va, vb;
#pragma unroll
            for (int j = 0; j < 4; ++j) {
                va[j] = (bf16_t)ra[i*2+0][j]; va[j+4] = (bf16_t)ra[i*2+1][j];
                vb[j] = (bf16_t)rb[i*2+0][j]; vb[j+4] = (bf16_t)rb[i*2+1][j];
            }
            *(bf16x8*)(&lA[buf][chunk*8]) = va;
            *(bf16x8*)(&lB[buf][chunk*8]) = vb;
        }
    };
    f32x4 acc[4][4] = {};
    auto compute = [&](int buf) {
#pragma unroll
        for (int ks = 0; ks < 2; ++ks) {
            bf16x8 af[4], bfr[4];
#pragma unroll
            for (int mi = 0; mi < 4; ++mi) {
                const int row = wm*64 + mi*16 + (lane & 15);
                const int cir = ks*4 + (lane >> 4);
                af[mi] = *(const bf16x8*)(&lA[buf][(row*8 + (cir ^ (row & 7)))*8]);
            }
#pragma unroll
            for (int ni = 0; ni < 4; ++ni) {
                const int row = wn*64 + ni*16 + (lane & 15);
                const int cir = ks*4 + (lane >> 4);
                bfr[ni] = *(const bf16x8*)(&lB[buf][(row*8 + (cir ^ (row & 7)))*8]);
            }
#pragma unroll
            for (int mi = 0; mi < 4; ++mi)
#pragma unroll
                for (int ni = 0; ni < 4; ++ni)
                    acc[mi][ni] = __builtin_amdgcn_mfma_f32_16x16x32_bf16(af[mi], bfr[ni], acc[mi][ni], 0, 0, 0);
        }
    };

    load_regs(0); store_lds(0);
    int cur = 0;
#pragma unroll 1
    for (int kt = 0; kt < FNKT; ++kt) {
        __syncthreads();
        if (kt + 1 < FNKT) load_regs(kt + 1);
        compute(cur);
        if (kt + 1 < FNKT) store_lds(cur ^ 1);
        cur ^= 1;
    }
    const int b = m0 / Ss, s0g = m0 % Ss;
    const int which = n0 >> 11, h = (n0 & (Ee - 1)) >> 7;
    float* obase = out + ((size_t)((which * Bb + b) * Hh + h) * Ss + s0g) * Dk;
#pragma unroll
    for (int mi = 0; mi < 4; ++mi)
#pragma unroll
        for (int ni = 0; ni < 4; ++ni)
#pragma unroll
            for (int r = 0; r < 4; ++r) {
                const int rowL = wm*64 + mi*16 + (lane >> 4)*4 + r;
                const int colL = wn*64 + ni*16 + (lane & 15);
                obase[(size_t)rowL * Dk + colL] = acc[mi][ni][r];
            }
}

// ---------------------------------------------------------------- launcher
extern "C" void kernel_launch(void* const* d_in, const int* in_sizes, int n_in,
                              void* d_out, int out_size, void* d_ws, size_t ws_size,
                              hipStream_t stream) {
    const float* x = (const float*)d_in[0];
    const float* w = (const float*)d_in[1];
    float* out = (float*)d_out;

    const size_t xb_bytes = (size_t)Mm * Kk * 2;
    const size_t wb_bytes = (size_t)Nn * Kk * 2;

    if (ws_size >= xb_bytes + wb_bytes) {
        bf16_t* xb = (bf16_t*)d_ws;
        bf16_t* wb = (bf16_t*)((char*)d_ws + xb_bytes);
        cast_f32_to_bf16<<<2048, 256, 0, stream>>>(x, w, xb, wb);
        qkv_tlp<<<TNWG, 256, 0, stream>>>(xb, wb, out);
    } else {
        dim3 grid(Nn / FTN, Mm / FTM);
        qkv_gemm_fb<<<grid, dim3(256), 0, stream>>>(x, w, out);
    }
}

// Round 9
// 452.668 us; speedup vs baseline: 1.2292x; 1.2292x over previous
//
#include <hip/hip_runtime.h>
#include <hip/hip_bf16.h>

// LinearPreMix: qkv = x @ W_qkv^T, split to q,k,v, reshape [B,S,E]->[B,H,S,DK]
// Pass 1: cast x,W fp32->bf16 into d_ws.
// Pass 2: r9 — 256x256 tile, 1024 threads = 16 waves of 64x64 (acc 64 VGPR)
//         -> 4 waves/SIMD (vs 2 before). K32-slice ring of 4 LDS slots,
//         stage 3-ahead, W_V4 every phase. Raises per-SIMD MFMA pressure to
//         amortize the ~700cyc/phase sync+stage wall that pinned r4-r7 at 44%.

constexpr int Bb = 4, Ss = 4096, Ee = 2048, Hh = 16, Dk = 128;
constexpr int Mm = Bb * Ss;   // 16384
constexpr int Nn = 3 * Ee;    // 6144
constexpr int Kk = Ee;        // 2048

typedef __bf16 bf16_t;
typedef __bf16 bf16x8 __attribute__((ext_vector_type(8)));
typedef float  f32x4  __attribute__((ext_vector_type(4)));

// ---------------------------------------------------------------- cast pass
__global__ __launch_bounds__(256)
void cast_f32_to_bf16(const float* __restrict__ x, const float* __restrict__ w,
                      bf16_t* __restrict__ xb, bf16_t* __restrict__ wb)
{
    const long XG = (long)Mm * Kk / 8;
    const long TG = XG + (long)Nn * Kk / 8;
    const long stride = (long)gridDim.x * blockDim.x;
    for (long g = (long)blockIdx.x * blockDim.x + threadIdx.x; g < TG; g += stride) {
        const float* s; bf16_t* d;
        if (g < XG) { s = x + g * 8;        d = xb + g * 8; }
        else        { s = w + (g - XG) * 8; d = wb + (g - XG) * 8; }
        f32x4 lo = *(const f32x4*)s;
        f32x4 hi = *(const f32x4*)(s + 4);
        bf16x8 o;
#pragma unroll
        for (int j = 0; j < 4; ++j) { o[j] = (bf16_t)lo[j]; o[j + 4] = (bf16_t)hi[j]; }
        *(bf16x8*)d = o;
    }
}

// ----------------------------------------------- 16-wave 256² ring-4 GEMM
constexpr int BM = 256, BN = 256;
constexpr int NBM = Mm / BM;     // 64
constexpr int NBN = Nn / BN;     // 24
constexpr int NWG = NBM * NBN;   // 1536
constexpr int NIT = Kk / 128;    // 16 iterations of 4 K32-slice phases

#define GLL16(GSRC, LDST) \
  __builtin_amdgcn_global_load_lds((const __attribute__((address_space(1))) void*)(GSRC), \
                                   (__attribute__((address_space(3))) void*)(LDST), 16, 0, 0)

// stage one K32 slice (A 256x32 + B 256x32): 2 GLL per thread (1024 thr)
#define STG(SLOT, OFS) do { \
    GLL16(srcA + (OFS), sA + (SLOT) * 8192 + wid * 512); \
    GLL16(srcB + (OFS), sB + (SLOT) * 8192 + wid * 512); \
} while (0)

#define W_V4 asm volatile("s_waitcnt vmcnt(4)" ::: "memory")

// phase J (slice s = it*4+J): read slot J, stage slot (J+3)&3 (slice s+3),
// barrier, 16 MFMA, W_V4 (confirms slice s+1), barrier.
#define PH(J, KB) do { \
    bf16x8 a[4], b[4]; \
    _Pragma("unroll") \
    for (int mf = 0; mf < 4; ++mf) { \
        int r = wm * 64 + mf * 16 + (lane & 15); \
        int q = r * 4 + (kc ^ ((r >> 1) & 3)); \
        a[mf] = *(const bf16x8*)(sA + (J) * 8192 + q * 8); \
    } \
    _Pragma("unroll") \
    for (int nf = 0; nf < 4; ++nf) { \
        int cr = wn * 64 + nf * 16 + (lane & 15); \
        int q = cr * 4 + (kc ^ ((cr >> 1) & 3)); \
        b[nf] = *(const bf16x8*)(sB + (J) * 8192 + q * 8); \
    } \
    STG(((J) + 3) & 3, ((KB) + ((J) + 3) * 32) & 2047); \
    __builtin_amdgcn_sched_barrier(0); \
    __builtin_amdgcn_s_barrier(); \
    __builtin_amdgcn_sched_barrier(0); \
    __builtin_amdgcn_s_setprio(1); \
    _Pragma("unroll") \
    for (int mf = 0; mf < 4; ++mf) { \
        _Pragma("unroll") \
        for (int nf = 0; nf < 4; ++nf) \
            acc[mf][nf] = __builtin_amdgcn_mfma_f32_16x16x32_bf16( \
                a[mf], b[nf], acc[mf][nf], 0, 0, 0); \
    } \
    __builtin_amdgcn_s_setprio(0); \
    W_V4; \
    __builtin_amdgcn_sched_barrier(0); \
    __builtin_amdgcn_s_barrier(); \
} while (0)

__global__ __launch_bounds__(1024, 4)
void qkv_w16(const bf16_t* __restrict__ xb, const bf16_t* __restrict__ wb,
             float* __restrict__ out)
{
    extern __shared__ __attribute__((aligned(16))) char smem_raw[];
    bf16_t* sA = (bf16_t*)smem_raw;                 // 4 slots x 8192 bf16 (64 KiB)
    bf16_t* sB = (bf16_t*)(smem_raw + 65536);       // 4 slots x 8192 bf16 (64 KiB)

    const int tid  = threadIdx.x;
    const int lane = tid & 63;
    const int wid  = tid >> 6;     // 0..15
    const int wm   = wid >> 2;     // 0..3 (64-row stripe)
    const int wn   = wid & 3;      // 0..3 (64-col stripe)
    const int kc   = lane >> 4;    // frag k-chunk 0..3

    // L2-cooperative mapping (r6): each XCD owns an 8-row bm stripe, bn-major.
    const int xcd = blockIdx.x & 7;
    const int i   = blockIdx.x >> 3;       // 0..191
    const int bm  = xcd * 8 + (i & 7);
    const int bn  = i >> 3;                // 0..23
    const int m0 = bm * BM, n0 = bn * BN;

    // pre-swizzled staging sources (linear LDS dest + swizzled global source)
    const int r0  = tid >> 2;                        // 0..255
    const int cl0 = (tid & 3) ^ ((r0 >> 1) & 3);
    const bf16_t* srcA = xb + (size_t)(m0 + r0) * Kk + cl0 * 8;
    const bf16_t* srcB = wb + (size_t)(n0 + r0) * Kk + cl0 * 8;

    f32x4 acc[4][4] = {};

    // prologue: stage slices 0,1,2 into slots 0,1,2; confirm slice 0
    STG(0, 0);
    STG(1, 32);
    STG(2, 64);
    asm volatile("s_waitcnt vmcnt(4)" ::: "memory");
    __builtin_amdgcn_s_barrier();

#pragma unroll 1
    for (int it = 0; it < NIT; ++it) {
        const int kb = it * 128;
        PH(0, kb);
        PH(1, kb);
        PH(2, kb);
        PH(3, kb);
    }

    // drain in-flight global_load_lds before waves exit (LDS reuse hazard)
    asm volatile("s_waitcnt vmcnt(0)" ::: "memory");

    // epilogue: wave's 64 cols live in one (which,b,h) panel half (DK=128).
    // nt stores, line-contiguous (mf,r,nf) order.
    const int which = n0 >> 11;
    const int hh    = ((n0 & (Ee - 1)) >> 7) + (wn >> 1);
    const int bbx   = m0 >> 12;
    const int srow  = (m0 & (Ss - 1)) + wm * 64;
    float* obase = out + (((size_t)(which * Bb + bbx) * Hh + hh) * Ss + srow) * Dk
                 + (wn & 1) * 64;

#pragma unroll
    for (int mf = 0; mf < 4; ++mf)
#pragma unroll
        for (int r = 0; r < 4; ++r)
#pragma unroll
            for (int nf = 0; nf < 4; ++nf) {
                const int row = mf * 16 + (lane >> 4) * 4 + r;
                const int col = nf * 16 + (lane & 15);
                __builtin_nontemporal_store(acc[mf][nf][r],
                                            &obase[(size_t)row * Dk + col]);
            }
}

// ------------------------------------------- fallback (fp32 reg staging)
constexpr int FTM = 128, FTN = 128, FTK = 64;
constexpr int FNKT = Kk / FTK;

__global__ __launch_bounds__(256, 2)
void qkv_gemm_fb(const float* __restrict__ x, const float* __restrict__ w,
                 float* __restrict__ out)
{
    __shared__ __attribute__((aligned(16))) bf16_t lA[2][FTM * FTK];
    __shared__ __attribute__((aligned(16))) bf16_t lB[2][FTN * FTK];

    const int tid = threadIdx.x, lane = tid & 63, wid = tid >> 6;
    const int wm = wid >> 1, wn = wid & 1;
    const int n0 = blockIdx.x * FTN, m0 = blockIdx.y * FTM;
    f32x4 ra[8], rb[8];

    auto load_regs = [&](int kt) {
        const int k0 = kt * FTK;
#pragma unroll
        for (int i = 0; i < 4; ++i) {
            const int c = tid + i * 256, row = c >> 3, cir = c & 7;
            const float* pa = x + (size_t)(m0 + row) * Kk + k0 + cir * 8;
            const float* pb = w + (size_t)(n0 + row) * Kk + k0 + cir * 8;
            ra[i*2+0] = *(const f32x4*)(pa); ra[i*2+1] = *(const f32x4*)(pa+4);
            rb[i*2+0] = *(const f32x4*)(pb); rb[i*2+1] = *(const f32x4*)(pb+4);
        }
    };
    auto store_lds = [&](int buf) {
#pragma unroll
        for (int i = 0; i < 4; ++i) {
            const int c = tid + i * 256, row = c >> 3, cir = c & 7;
            const int chunk = row * 8 + (cir ^ (row & 7));
            bf16x8 va, vb;
#pragma unroll
            for (int j = 0; j < 4; ++j) {
                va[j] = (bf16_t)ra[i*2+0][j]; va[j+4] = (bf16_t)ra[i*2+1][j];
                vb[j] = (bf16_t)rb[i*2+0][j]; vb[j+4] = (bf16_t)rb[i*2+1][j];
            }
            *(bf16x8*)(&lA[buf][chunk*8]) = va;
            *(bf16x8*)(&lB[buf][chunk*8]) = vb;
        }
    };
    f32x4 acc[4][4] = {};
    auto compute = [&](int buf) {
#pragma unroll
        for (int ks = 0; ks < 2; ++ks) {
            bf16x8 af[4], bfr[4];
#pragma unroll
            for (int mi = 0; mi < 4; ++mi) {
                const int row = wm*64 + mi*16 + (lane & 15);
                const int cir = ks*4 + (lane >> 4);
                af[mi] = *(const bf16x8*)(&lA[buf][(row*8 + (cir ^ (row & 7)))*8]);
            }
#pragma unroll
            for (int ni = 0; ni < 4; ++ni) {
                const int row = wn*64 + ni*16 + (lane & 15);
                const int cir = ks*4 + (lane >> 4);
                bfr[ni] = *(const bf16x8*)(&lB[buf][(row*8 + (cir ^ (row & 7)))*8]);
            }
#pragma unroll
            for (int mi = 0; mi < 4; ++mi)
#pragma unroll
                for (int ni = 0; ni < 4; ++ni)
                    acc[mi][ni] = __builtin_amdgcn_mfma_f32_16x16x32_bf16(af[mi], bfr[ni], acc[mi][ni], 0, 0, 0);
        }
    };

    load_regs(0); store_lds(0);
    int cur = 0;
#pragma unroll 1
    for (int kt = 0; kt < FNKT; ++kt) {
        __syncthreads();
        if (kt + 1 < FNKT) load_regs(kt + 1);
        compute(cur);
        if (kt + 1 < FNKT) store_lds(cur ^ 1);
        cur ^= 1;
    }
    const int b = m0 / Ss, s0g = m0 % Ss;
    const int which = n0 >> 11, h = (n0 & (Ee - 1)) >> 7;
    float* obase = out + ((size_t)((which * Bb + b) * Hh + h) * Ss + s0g) * Dk;
#pragma unroll
    for (int mi = 0; mi < 4; ++mi)
#pragma unroll
        for (int ni = 0; ni < 4; ++ni)
#pragma unroll
            for (int r = 0; r < 4; ++r) {
                const int rowL = wm*64 + mi*16 + (lane >> 4)*4 + r;
                const int colL = wn*64 + ni*16 + (lane & 15);
                obase[(size_t)rowL * Dk + colL] = acc[mi][ni][r];
            }
}

// ---------------------------------------------------------------- launcher
extern "C" void kernel_launch(void* const* d_in, const int* in_sizes, int n_in,
                              void* d_out, int out_size, void* d_ws, size_t ws_size,
                              hipStream_t stream) {
    const float* x = (const float*)d_in[0];
    const float* w = (const float*)d_in[1];
    float* out = (float*)d_out;

    const size_t xb_bytes = (size_t)Mm * Kk * 2;
    const size_t wb_bytes = (size_t)Nn * Kk * 2;

    if (ws_size >= xb_bytes + wb_bytes) {
        bf16_t* xb = (bf16_t*)d_ws;
        bf16_t* wb = (bf16_t*)((char*)d_ws + xb_bytes);
        cast_f32_to_bf16<<<2048, 256, 0, stream>>>(x, w, xb, wb);
        hipFuncSetAttribute((const void*)qkv_w16,
                            hipFuncAttributeMaxDynamicSharedMemorySize, 131072);
        qkv_w16<<<NWG, 1024, 131072, stream>>>(xb, wb, out);
    } else {
        dim3 grid(Nn / FTN, Mm / FTM);
        qkv_gemm_fb<<<grid, dim3(256), 0, stream>>>(x, w, out);
    }
}